// Round 1
// baseline (1467.754 us; speedup 1.0000x reference)
//
#include <hip/hip_runtime.h>
#include <hip/hip_bf16.h>

// Problem constants (match reference setup_inputs)
constexpr int N_NODES = 500000;
constexpr int N_Q     = 500000;
constexpr int H       = 8;
constexpr int MH      = 8;
constexpr int FEAT    = H * MH;   // 64 floats per query / per node column

// One wave (64 lanes) per query.
// lane = h*8 + mh.
//  - q_phi[q][h][mh]      : flat q*64 + lane       (coalesced 256B per wave)
//  - phi_k_pos[h][mh][j]  : flat lane*N_NODES + j  (64-line scatter, relies on L2/L3)
//  - reduce over mh within 8-lane groups via shfl_xor
//  - lanes with mh==0 apply degree clamp + divide, store pos/neg outputs.
__global__ __launch_bounds__(256, 4) void iskde_gather_kernel(
    const float* __restrict__ q_phi,
    const float* __restrict__ pk_pos,
    const float* __restrict__ pk_neg,
    const float* __restrict__ deg_pos,
    const float* __restrict__ deg_neg,
    const int*   __restrict__ k_idx,
    float*       __restrict__ out)
{
    const int wave_in_blk = threadIdx.x >> 6;
    const int lane        = threadIdx.x & 63;
    const int q           = blockIdx.x * 4 + wave_in_blk;
    if (q >= N_Q) return;

    const int j = k_idx[q];   // uniform across the wave -> broadcast

    // coalesced q_phi read
    const float qv = q_phi[(size_t)q * FEAT + lane];

    // scattered gathers (stride N_NODES between lanes)
    const size_t col = (size_t)lane * (size_t)N_NODES + (size_t)j;
    const float pv = pk_pos[col];
    const float nv = pk_neg[col];

    float sp = qv * pv;
    float sn = qv * nv;

    // reduce over mh (8 consecutive lanes share one head)
    sp += __shfl_xor(sp, 1, 64);
    sn += __shfl_xor(sn, 1, 64);
    sp += __shfl_xor(sp, 2, 64);
    sn += __shfl_xor(sn, 2, 64);
    sp += __shfl_xor(sp, 4, 64);
    sn += __shfl_xor(sn, 4, 64);

    if ((lane & 7) == 0) {
        const int h = lane >> 3;
        const float dp = fmaxf(deg_pos[(size_t)j * H + h], 1.0f);
        const float dn = fmaxf(deg_neg[(size_t)j * H + h], 1.0f);
        const size_t o = (size_t)q * H + h;
        out[o]                     = sp / dp;   // out_pos
        out[(size_t)N_Q * H + o]   = sn / dn;   // out_neg
    }
}

extern "C" void kernel_launch(void* const* d_in, const int* in_sizes, int n_in,
                              void* d_out, int out_size, void* d_ws, size_t ws_size,
                              hipStream_t stream) {
    const float* q_phi   = (const float*)d_in[0];
    const float* pk_pos  = (const float*)d_in[1];
    const float* pk_neg  = (const float*)d_in[2];
    const float* deg_pos = (const float*)d_in[3];
    const float* deg_neg = (const float*)d_in[4];
    const int*   k_idx   = (const int*)d_in[5];
    float*       out     = (float*)d_out;

    // 4 waves (queries) per 256-thread block
    const int blocks = (N_Q + 3) / 4;
    iskde_gather_kernel<<<blocks, 256, 0, stream>>>(
        q_phi, pk_pos, pk_neg, deg_pos, deg_neg, k_idx, out);
}

// Round 2
// 531.403 us; speedup vs baseline: 2.7620x; 2.7620x over previous
//
#include <hip/hip_runtime.h>
#include <hip/hip_bf16.h>

constexpr int N_NODES = 500000;
constexpr int N_Q     = 500000;
constexpr int H       = 8;
constexpr int FEAT    = 64;                      // H * MH
constexpr int TILES   = (N_NODES + 63) / 64;     // 7813

// ---------------------------------------------------------------------------
// Kernel 1: transpose phi_k[64][N] -> pk_t[N][64] (node-major), pos & neg.
// 64x64 float tile via LDS (pad 65 -> 2-way bank aliasing only, free).
// Both the global read (256B rows of src) and global write (256B rows of dst)
// are fully coalesced.
// ---------------------------------------------------------------------------
__global__ __launch_bounds__(256) void transpose_pk(
    const float* __restrict__ pk_pos,
    const float* __restrict__ pk_neg,
    float* __restrict__ dst)                     // [2][N_NODES][64]
{
    __shared__ float lds[64 * 65];
    const int t  = threadIdx.x;
    const int n0 = blockIdx.x * 64;
    const float* src = blockIdx.y ? pk_neg : pk_pos;
    float* d = dst + (size_t)blockIdx.y * (size_t)N_NODES * FEAT;

    {
        const int  n  = t & 63;
        const bool ok = (n0 + n) < N_NODES;
        for (int f = (t >> 6); f < 64; f += 4)
            lds[f * 65 + n] = ok ? src[(size_t)f * N_NODES + n0 + n] : 0.0f;
    }
    __syncthreads();
    {
        const int f  = t & 63;
        const int nb = (t >> 6) * 16;
        for (int r = 0; r < 16; ++r) {
            const int n = nb + r;
            if (n0 + n < N_NODES)
                d[(size_t)(n0 + n) * FEAT + f] = lds[f * 65 + n];
        }
    }
}

// ---------------------------------------------------------------------------
// Kernel 2: one wave per query; gather is now 256B contiguous per matrix.
// ---------------------------------------------------------------------------
__global__ __launch_bounds__(256, 4) void iskde_main_kernel(
    const float* __restrict__ q_phi,
    const float* __restrict__ pk_t,              // [2][N_NODES][64]
    const float* __restrict__ deg_pos,
    const float* __restrict__ deg_neg,
    const int*   __restrict__ k_idx,
    float*       __restrict__ out)
{
    const int wave_in_blk = threadIdx.x >> 6;
    const int lane        = threadIdx.x & 63;
    const int q           = blockIdx.x * 4 + wave_in_blk;
    if (q >= N_Q) return;

    const int j = k_idx[q];                      // wave-uniform

    const float qv = q_phi[(size_t)q * FEAT + lane];            // coalesced
    const float pv = pk_t[(size_t)j * FEAT + lane];             // 256B dense
    const float nv = pk_t[(size_t)(N_NODES + j) * FEAT + lane]; // 256B dense

    float sp = qv * pv;
    float sn = qv * nv;

    sp += __shfl_xor(sp, 1, 64);
    sn += __shfl_xor(sn, 1, 64);
    sp += __shfl_xor(sp, 2, 64);
    sn += __shfl_xor(sn, 2, 64);
    sp += __shfl_xor(sp, 4, 64);
    sn += __shfl_xor(sn, 4, 64);

    if ((lane & 7) == 0) {
        const int h = lane >> 3;
        const float dp = fmaxf(deg_pos[(size_t)j * H + h], 1.0f);
        const float dn = fmaxf(deg_neg[(size_t)j * H + h], 1.0f);
        const size_t o = (size_t)q * H + h;
        out[o]                   = sp / dp;
        out[(size_t)N_Q * H + o] = sn / dn;
    }
}

// ---------------------------------------------------------------------------
// Fallback (R0 path) if workspace is too small for the transposed copies.
// ---------------------------------------------------------------------------
__global__ __launch_bounds__(256, 4) void iskde_gather_kernel(
    const float* __restrict__ q_phi,
    const float* __restrict__ pk_pos,
    const float* __restrict__ pk_neg,
    const float* __restrict__ deg_pos,
    const float* __restrict__ deg_neg,
    const int*   __restrict__ k_idx,
    float*       __restrict__ out)
{
    const int wave_in_blk = threadIdx.x >> 6;
    const int lane        = threadIdx.x & 63;
    const int q           = blockIdx.x * 4 + wave_in_blk;
    if (q >= N_Q) return;

    const int j = k_idx[q];
    const float qv = q_phi[(size_t)q * FEAT + lane];
    const size_t col = (size_t)lane * (size_t)N_NODES + (size_t)j;
    const float pv = pk_pos[col];
    const float nv = pk_neg[col];

    float sp = qv * pv;
    float sn = qv * nv;
    sp += __shfl_xor(sp, 1, 64);
    sn += __shfl_xor(sn, 1, 64);
    sp += __shfl_xor(sp, 2, 64);
    sn += __shfl_xor(sn, 2, 64);
    sp += __shfl_xor(sp, 4, 64);
    sn += __shfl_xor(sn, 4, 64);

    if ((lane & 7) == 0) {
        const int h = lane >> 3;
        const float dp = fmaxf(deg_pos[(size_t)j * H + h], 1.0f);
        const float dn = fmaxf(deg_neg[(size_t)j * H + h], 1.0f);
        const size_t o = (size_t)q * H + h;
        out[o]                   = sp / dp;
        out[(size_t)N_Q * H + o] = sn / dn;
    }
}

extern "C" void kernel_launch(void* const* d_in, const int* in_sizes, int n_in,
                              void* d_out, int out_size, void* d_ws, size_t ws_size,
                              hipStream_t stream) {
    const float* q_phi   = (const float*)d_in[0];
    const float* pk_pos  = (const float*)d_in[1];
    const float* pk_neg  = (const float*)d_in[2];
    const float* deg_pos = (const float*)d_in[3];
    const float* deg_neg = (const float*)d_in[4];
    const int*   k_idx   = (const int*)d_in[5];
    float*       out     = (float*)d_out;

    const size_t need = (size_t)2 * N_NODES * FEAT * sizeof(float);  // 256 MB

    if (ws_size >= need) {
        float* pk_t = (float*)d_ws;
        dim3 tgrid(TILES, 2);
        transpose_pk<<<tgrid, 256, 0, stream>>>(pk_pos, pk_neg, pk_t);

        const int blocks = (N_Q + 3) / 4;
        iskde_main_kernel<<<blocks, 256, 0, stream>>>(
            q_phi, pk_t, deg_pos, deg_neg, k_idx, out);
    } else {
        const int blocks = (N_Q + 3) / 4;
        iskde_gather_kernel<<<blocks, 256, 0, stream>>>(
            q_phi, pk_pos, pk_neg, deg_pos, deg_neg, k_idx, out);
    }
}

// Round 3
// 450.578 us; speedup vs baseline: 3.2575x; 1.1794x over previous
//
#include <hip/hip_runtime.h>
#include <hip/hip_bf16.h>

constexpr int N_NODES = 500000;
constexpr int N_Q     = 500000;
constexpr int H       = 8;
constexpr int FEAT    = 64;                      // H * MH
constexpr int TILES   = (N_NODES + 63) / 64;     // 7813

// ---------------------------------------------------------------------------
// Kernel 1: transpose phi_k[64][N] -> pk_t[N][64] (node-major), pos & neg.
// float4 on both global sides; 64x64 tile via LDS (pad 65 -> 2-way alias, free).
//  phase 1: wave reads 4 rows x 256B (float4 along n)
//  phase 2: wave writes 4 node-rows x 256B = 1KB contiguous (float4 along f)
// ---------------------------------------------------------------------------
__global__ __launch_bounds__(256) void transpose_pk(
    const float* __restrict__ pk_pos,
    const float* __restrict__ pk_neg,
    float* __restrict__ dst)                     // [2][N_NODES][64]
{
    __shared__ float lds[64 * 65];
    const int t  = threadIdx.x;
    const int n0 = blockIdx.x * 64;
    const float* src = blockIdx.y ? pk_neg : pk_pos;
    float* d = dst + (size_t)blockIdx.y * (size_t)N_NODES * FEAT;

    const int nrem = N_NODES - n0;               // nodes in this tile (<=64)

    // phase 1: global (f-major rows) -> LDS
    {
        const int n4 = (t & 15) * 4;             // 0,4,...,60
        const int fb = t >> 4;                   // 0..15
        for (int it = 0; it < 4; ++it) {
            const int f = fb + it * 16;
            float4 v = make_float4(0.f, 0.f, 0.f, 0.f);
            const float* s = src + (size_t)f * N_NODES + n0 + n4;
            if (n4 + 3 < nrem) {
                v = *(const float4*)s;
            } else if (n4 < nrem) {
                v.x = s[0];
                if (n4 + 1 < nrem) v.y = s[1];
                if (n4 + 2 < nrem) v.z = s[2];
            }
            float* l = &lds[f * 65 + n4];
            l[0] = v.x; l[1] = v.y; l[2] = v.z; l[3] = v.w;
        }
    }
    __syncthreads();

    // phase 2: LDS -> global (n-major rows), 1KB contiguous per wave instr
    {
        const int f4 = (t & 15) * 4;             // 0,4,...,60
        const int nb = t >> 4;                   // 0..15
        for (int it = 0; it < 4; ++it) {
            const int n = nb + it * 16;
            if (n < nrem) {
                float4 v;
                v.x = lds[(f4 + 0) * 65 + n];
                v.y = lds[(f4 + 1) * 65 + n];
                v.z = lds[(f4 + 2) * 65 + n];
                v.w = lds[(f4 + 3) * 65 + n];
                *(float4*)(d + (size_t)(n0 + n) * FEAT + f4) = v;
            }
        }
    }
}

// ---------------------------------------------------------------------------
// Kernel 2: thread per (q,h). All global accesses vectorized/coalesced:
//   q_phi : 2KB contiguous per wave (2x float4/thread)
//   pk_t  : 8 node-columns x 256B per wave (4x float4/thread)
//   out   : 256B contiguous dword stores per wave
// No shfl, no LDS.
// ---------------------------------------------------------------------------
__global__ __launch_bounds__(256) void iskde_main2(
    const float* __restrict__ q_phi,
    const float* __restrict__ pk_t,              // [2][N_NODES][64]
    const float* __restrict__ deg_pos,
    const float* __restrict__ deg_neg,
    const int*   __restrict__ k_idx,
    float*       __restrict__ out)
{
    const int i = blockIdx.x * 256 + threadIdx.x;   // flat (q,h); grid exact
    const int q = i >> 3;
    const int h = i & 7;

    const int j = k_idx[q];

    const float4* qp = (const float4*)(q_phi + (size_t)q * FEAT + h * 8);
    const float4* pp = (const float4*)(pk_t + (size_t)j * FEAT + h * 8);
    const float4* pn = (const float4*)(pk_t + ((size_t)N_NODES + (size_t)j) * FEAT + h * 8);

    const float4 a0 = qp[0], a1 = qp[1];
    const float4 b0 = pp[0], b1 = pp[1];
    const float4 c0 = pn[0], c1 = pn[1];

    float sp = a0.x*b0.x + a0.y*b0.y + a0.z*b0.z + a0.w*b0.w
             + a1.x*b1.x + a1.y*b1.y + a1.z*b1.z + a1.w*b1.w;
    float sn = a0.x*c0.x + a0.y*c0.y + a0.z*c0.z + a0.w*c0.w
             + a1.x*c1.x + a1.y*c1.y + a1.z*c1.z + a1.w*c1.w;

    const float dp = fmaxf(deg_pos[(size_t)j * H + h], 1.0f);
    const float dn = fmaxf(deg_neg[(size_t)j * H + h], 1.0f);

    __builtin_nontemporal_store(sp / dp, &out[i]);
    __builtin_nontemporal_store(sn / dn, &out[(size_t)N_Q * H + i]);
}

// ---------------------------------------------------------------------------
// Fallback (R0 path) if workspace is too small for the transposed copies.
// ---------------------------------------------------------------------------
__global__ __launch_bounds__(256, 4) void iskde_gather_kernel(
    const float* __restrict__ q_phi,
    const float* __restrict__ pk_pos,
    const float* __restrict__ pk_neg,
    const float* __restrict__ deg_pos,
    const float* __restrict__ deg_neg,
    const int*   __restrict__ k_idx,
    float*       __restrict__ out)
{
    const int wave_in_blk = threadIdx.x >> 6;
    const int lane        = threadIdx.x & 63;
    const int q           = blockIdx.x * 4 + wave_in_blk;
    if (q >= N_Q) return;

    const int j = k_idx[q];
    const float qv = q_phi[(size_t)q * FEAT + lane];
    const size_t col = (size_t)lane * (size_t)N_NODES + (size_t)j;
    const float pv = pk_pos[col];
    const float nv = pk_neg[col];

    float sp = qv * pv;
    float sn = qv * nv;
    sp += __shfl_xor(sp, 1, 64);
    sn += __shfl_xor(sn, 1, 64);
    sp += __shfl_xor(sp, 2, 64);
    sn += __shfl_xor(sn, 2, 64);
    sp += __shfl_xor(sp, 4, 64);
    sn += __shfl_xor(sn, 4, 64);

    if ((lane & 7) == 0) {
        const int h = lane >> 3;
        const float dp = fmaxf(deg_pos[(size_t)j * H + h], 1.0f);
        const float dn = fmaxf(deg_neg[(size_t)j * H + h], 1.0f);
        const size_t o = (size_t)q * H + h;
        out[o]                   = sp / dp;
        out[(size_t)N_Q * H + o] = sn / dn;
    }
}

extern "C" void kernel_launch(void* const* d_in, const int* in_sizes, int n_in,
                              void* d_out, int out_size, void* d_ws, size_t ws_size,
                              hipStream_t stream) {
    const float* q_phi   = (const float*)d_in[0];
    const float* pk_pos  = (const float*)d_in[1];
    const float* pk_neg  = (const float*)d_in[2];
    const float* deg_pos = (const float*)d_in[3];
    const float* deg_neg = (const float*)d_in[4];
    const int*   k_idx   = (const int*)d_in[5];
    float*       out     = (float*)d_out;

    const size_t need = (size_t)2 * N_NODES * FEAT * sizeof(float);  // 256 MB

    if (ws_size >= need) {
        float* pk_t = (float*)d_ws;
        dim3 tgrid(TILES, 2);
        transpose_pk<<<tgrid, 256, 0, stream>>>(pk_pos, pk_neg, pk_t);

        const int blocks = (N_Q * H) / 256;      // 15625, exact
        iskde_main2<<<blocks, 256, 0, stream>>>(
            q_phi, pk_t, deg_pos, deg_neg, k_idx, out);
    } else {
        const int blocks = (N_Q + 3) / 4;
        iskde_gather_kernel<<<blocks, 256, 0, stream>>>(
            q_phi, pk_pos, pk_neg, deg_pos, deg_neg, k_idx, out);
    }
}